// Round 6
// baseline (453.007 us; speedup 1.0000x reference)
//
#include <hip/hip_runtime.h>
#include <stdint.h>

// Round-10: two-kernel split; kill the latency-serial dependent phases.
// Evidence: 6 structures all land 116-293us with every pipe <35% busy; VGPR
// counts (44/52/88/104) prove the allocator never holds enough loads in
// flight for in-block pipelining. Fix: make every kernel's waves independent.
//  K1 stats_k (single data touch): per 64-row chunk, rowsums are CHUNK-LOCAL,
//    so a[p]=sum_d T[d][p]*rsR[d] accumulates from the just-loaded registers
//    after one barrier/chunk. Tiny LDS (6KB) + tiny VGPR -> 3 blocks/CU,
//    27 waves: latency hidden by TLP. Writes q|e|a|b to ws, out[g] directly.
//  K2 fuse_k: topk weights from ws, then a BARRIER-FREE 8-chunk re-read
//    (L3-hot, 221MB < 256MB L3) for the fuse dots.
#define NGRP 1500
#define DD   512
#define PP   36
#define DP   (DD*PP)          // 18432 floats per tensor per group
#define NT   576              // 9 waves; one chunk = 64 rows = NT float4/tensor
#define NK   8
#define WSG  144              // ws floats per group: q[36]|e[36]|a[36]|b[36]
#define SCALE_CLS 7.0f
#define EPS 1e-12f

__device__ __forceinline__ float waveRed(float x){
  #pragma unroll
  for (int off = 32; off; off >>= 1) x += __shfl_xor(x, off, 64);
  return x;
}

__global__ __launch_bounds__(NT)
void stats_k(const float* __restrict__ gtrain, const float* __restrict__ gtest,
             float* __restrict__ out, float* __restrict__ ws)
{
  __shared__ float s_rsT[DD], s_rsR[DD];         // rowsums (atomic, 9-way)
  __shared__ float s_q[PP], s_e[PP], s_a[PP], s_b[PP];
  __shared__ float s_red[24];

  const int t    = threadIdx.x;
  const int lane = t & 63;
  const int wave = t >> 6;
  const int g    = blockIdx.x;
  const int c    = t % 9;                        // fixed column-block
  const int r0   = t / 9;                        // row within chunk

  const float4* gT4 = (const float4*)(gtest  + (size_t)g * DP);
  const float4* gR4 = (const float4*)(gtrain + (size_t)g * DP);

  float4 x = gT4[t], y = gR4[t];                 // chunk 0 in flight over init
  if (t < DD) { s_rsT[t] = 0.f; s_rsR[t] = 0.f; }
  if (t < PP) { s_q[t] = 0.f; s_e[t] = 0.f; s_a[t] = 0.f; s_b[t] = 0.f; }
  __syncthreads();

  float qx=0,qy=0,qz=0,qw=0, ex=0,ey=0,ez=0,ew=0;
  float ax=0,ay=0,az=0,aw=0, bx=0,by=0,bz=0,bw=0;
  #pragma unroll
  for (int k = 0; k < NK; ++k) {
    const int d0 = r0 + 64*k;                    // (t+576k)/9 == t/9 + 64k
    atomicAdd(&s_rsT[d0], (x.x + x.y) + (x.z + x.w));
    atomicAdd(&s_rsR[d0], (y.x + y.y) + (y.z + y.w));
    qx += x.x*x.x; qy += x.y*x.y; qz += x.z*x.z; qw += x.w*x.w;
    ex += y.x*y.x; ey += y.y*y.y; ez += y.z*y.z; ew += y.w*y.w;
    float4 xn = {0,0,0,0}, yn = {0,0,0,0};
    if (k + 1 < NK) { xn = gT4[t + NT*(k+1)]; yn = gR4[t + NT*(k+1)]; } // prefetch
    __syncthreads();                             // chunk-k rowsums final
    const float rr = s_rsR[d0], rt = s_rsT[d0];  // 9-lane broadcast read
    ax += x.x*rr; ay += x.y*rr; az += x.z*rr; aw += x.w*rr;
    bx += y.x*rt; by += y.y*rt; bz += y.z*rt; bw += y.w*rt;
    x = xn; y = yn;
  }

  {
    const int p0 = 4*c;
    atomicAdd(&s_q[p0+0], qx); atomicAdd(&s_q[p0+1], qy);
    atomicAdd(&s_q[p0+2], qz); atomicAdd(&s_q[p0+3], qw);
    atomicAdd(&s_e[p0+0], ex); atomicAdd(&s_e[p0+1], ey);
    atomicAdd(&s_e[p0+2], ez); atomicAdd(&s_e[p0+3], ew);
    atomicAdd(&s_a[p0+0], ax); atomicAdd(&s_a[p0+1], ay);
    atomicAdd(&s_a[p0+2], az); atomicAdd(&s_a[p0+3], aw);
    atomicAdd(&s_b[p0+0], bx); atomicAdd(&s_b[p0+1], by);
    atomicAdd(&s_b[p0+2], bz); atomicAdd(&s_b[p0+3], bw);
  }

  // mean-cosine from rowsums (1/36 factors cancel); rsT/rsR final post-loop
  if (t < DD) {
    float rT = s_rsT[t], rR = s_rsR[t];
    float m2 = waveRed(rT * rT);
    float r2 = waveRed(rR * rR);
    float mr = waveRed(rT * rR);
    if (lane == 0) { s_red[wave] = m2; s_red[8+wave] = r2; s_red[16+wave] = mr; }
  }
  __syncthreads();

  if (t == 0) {
    float m2 = 0.f, r2 = 0.f, mr = 0.f;
    #pragma unroll
    for (int w = 0; w < 8; ++w) { m2 += s_red[w]; r2 += s_red[8+w]; mr += s_red[16+w]; }
    out[g] = SCALE_CLS * mr / (fmaxf(sqrtf(m2), EPS) * fmaxf(sqrtf(r2), EPS));
  }
  float* wsg = ws + (size_t)g * WSG;
  if (t < WSG) {
    float v = (t < 36) ? s_q[t] : (t < 72) ? s_e[t-36]
            : (t < 108) ? s_a[t-72] : s_b[t-108];
    wsg[t] = v;
  }
}

__global__ __launch_bounds__(NT)
void fuse_k(const float* __restrict__ gtrain, const float* __restrict__ gtest,
            const int* __restrict__ Kp, float* __restrict__ out,
            const float* __restrict__ ws)
{
  __shared__ float s_u[DD], s_v[DD];             // fuse row dots (atomic)
  __shared__ float s_nt[PP], s_nr[PP], s_st[PP], s_sr[PP];
  __shared__ __align__(16) float s_wt[PP], s_wr[PP];
  __shared__ float s_red[24];

  const int t    = threadIdx.x;
  const int lane = t & 63;
  const int wave = t >> 6;
  const int g    = blockIdx.x;
  const int c    = t % 9;
  const int r0   = t / 9;
  const int K    = Kp[0];

  const float4* gT4 = (const float4*)(gtest  + (size_t)g * DP);
  const float4* gR4 = (const float4*)(gtrain + (size_t)g * DP);

  float4 x = gT4[t], y = gR4[t];                 // chunk 0 in flight over topk
  if (t < DD) { s_u[t] = 0.f; s_v[t] = 0.f; }

  const float* wsg = ws + (size_t)g * WSG;
  if (wave < 2 && lane < PP) {
    float q  = wave ? wsg[36 + lane]  : wsg[lane];
    float dm = wave ? wsg[108 + lane] : wsg[72 + lane];
    float n  = fmaxf(sqrtf(q), EPS);
    float sc = dm / n;
    if (wave) { s_nr[lane] = n; s_sr[lane] = sc; }
    else      { s_nt[lane] = n; s_st[lane] = sc; }
  }
  __syncthreads();

  // top-K via ranks (jnp ties: lower index wins) -> fuse weights
  if (wave < 2 && lane < PP) {
    const float* sc = wave ? s_sr : s_st;
    const float* nn = wave ? s_nr : s_nt;
    float*       w  = wave ? s_wr : s_wt;
    float mine = sc[lane];
    int rank = 0;
    #pragma unroll
    for (int p = 0; p < PP; ++p) {
      float o = sc[p];
      rank += ((o > mine) || (o == mine && p < lane)) ? 1 : 0;
    }
    w[lane] = (rank < K) ? (1.0f / nn[lane]) : 0.f;
  }
  __syncthreads();

  // barrier-free fuse loop: u_d = T[d].wt, v_d = R[d].wr  (L3-hot re-read)
  const float4 wt4 = *(const float4*)&s_wt[4*c];
  const float4 wr4 = *(const float4*)&s_wr[4*c];
  #pragma unroll
  for (int k = 0; k < NK; ++k) {
    const int d0 = r0 + 64*k;
    float up = x.x*wt4.x + x.y*wt4.y + x.z*wt4.z + x.w*wt4.w;
    float vp = y.x*wr4.x + y.y*wr4.y + y.z*wr4.z + y.w*wr4.w;
    atomicAdd(&s_u[d0], up);
    atomicAdd(&s_v[d0], vp);
    if (k + 1 < NK) { x = gT4[t + NT*(k+1)]; y = gR4[t + NT*(k+1)]; }
  }
  __syncthreads();

  if (t < DD) {
    float u = s_u[t], v = s_v[t];
    float u2 = waveRed(u * u);
    float v2 = waveRed(v * v);
    float uv = waveRed(u * v);
    if (lane == 0) { s_red[wave] = u2; s_red[8+wave] = v2; s_red[16+wave] = uv; }
  }
  __syncthreads();

  if (t == 0) {
    float u2 = 0.f, v2 = 0.f, uv = 0.f;
    #pragma unroll
    for (int w = 0; w < 8; ++w) { u2 += s_red[w]; v2 += s_red[8+w]; uv += s_red[16+w]; }
    out[NGRP + g] = SCALE_CLS * uv / (fmaxf(sqrtf(u2), EPS) * fmaxf(sqrtf(v2), EPS));
  }
}

extern "C" void kernel_launch(void* const* d_in, const int* in_sizes, int n_in,
                              void* d_out, int out_size, void* d_ws, size_t ws_size,
                              hipStream_t stream)
{
  const float* ftrain = (const float*)d_in[0];
  const float* ftest  = (const float*)d_in[1];
  const int*   Kp     = (const int*)d_in[2];
  float*       out    = (float*)d_out;
  float*       ws     = (float*)d_ws;            // needs 1500*144*4B = 864 KB
  stats_k<<<NGRP, NT, 0, stream>>>(ftrain, ftest, out, ws);
  fuse_k <<<NGRP, NT, 0, stream>>>(ftrain, ftest, Kp, out, ws);
}